// Round 10
// baseline (937.906 us; speedup 1.0000x reference)
//
#include <hip/hip_runtime.h>
#include <hip/hip_bf16.h>

typedef unsigned short u16;
typedef __attribute__((ext_vector_type(8))) short bf16x8;
typedef __attribute__((ext_vector_type(4))) float f32x4;
typedef __attribute__((ext_vector_type(4))) float vfloat4;
typedef __attribute__((ext_vector_type(4))) unsigned short ushort4v;
typedef __attribute__((ext_vector_type(8))) unsigned short ushort8v;

#define DEV __device__ __forceinline__
#define AS1 __attribute__((address_space(1)))
#define AS3 __attribute__((address_space(3)))

#define BARRIER()  __builtin_amdgcn_s_barrier()
#define LGKM0()    asm volatile("s_waitcnt lgkmcnt(0)" ::: "memory")
#define VMCNT0()   asm volatile("s_waitcnt vmcnt(0)" ::: "memory")
#define VMCNT4()   asm volatile("s_waitcnt vmcnt(4)" ::: "memory")
#define SCHED0()   __builtin_amdgcn_sched_barrier(0)

DEV u16 f2bf(float f) {
    union { float f; unsigned u; } v; v.f = f;
    unsigned r = v.u + 0x7FFFu + ((v.u >> 16) & 1u);
    return (u16)(r >> 16);
}

DEV void gload_lds16(const void* g, void* l) {
    __builtin_amdgcn_global_load_lds((const AS1 unsigned int*)g,
                                     (AS3 unsigned int*)l, 16, 0, 0);
}

static constexpr int KDIM = 1024;   // embed
static constexpr int NROW = 65536;  // B*S

// ---------------- fp32 -> bf16 convert (memory-bound) ----------------
__global__ __launch_bounds__(256)
void cvt_f32_bf16(const float* __restrict__ src, u16* __restrict__ dst, unsigned n8)
{
    unsigned stride = gridDim.x * blockDim.x;
    for (unsigned i = blockIdx.x * blockDim.x + threadIdx.x; i < n8; i += stride) {
        size_t base = (size_t)i * 8;
        vfloat4 a = *(const vfloat4*)(src + base);
        vfloat4 b = *(const vfloat4*)(src + base + 4);
        ushort8v o;
#pragma unroll
        for (int j = 0; j < 4; ++j) { o[j] = f2bf(a[j]); o[j + 4] = f2bf(b[j]); }
        *(ushort8v*)(dst + base) = o;
    }
}

// ---------------- 8-phase 256^2 bf16 GEMM ------------------------------------
// Y = Xb @ Wb^T + b. BM=BN=256, BK=64, 16 K-tiles, 8 waves (2Mx4N).
// FULL-SLOT ledger (reads touch both halves of a slot across waves, so a slot
// must be fully landed before ANY read of it — round-9's per-half ledger raced):
//   per iter i (kt_a=2i -> slot0, kt_b=2i+1 -> slot1):
//     P1/P2 stage As1(kt_b)      drained P4 vmcnt(4)   read P5/P7  (ages 3,2)
//     P3/P4 stage Bs0(kt_a+2)    drained P8 vmcnt(4)   read P1'    (ages 5,4)
//     P5/P6 stage As0(kt_a+2)    drained P8 vmcnt(4)   read P1'    (ages 3,2)
//     P7/P8 stage Bs1(kt_b+2)    drained P4' vmcnt(4)  read P5'    (ages 5,4)
//   vmcnt(4) leaves the 2 newest half-tiles in flight; placed BEFORE the mid
//   barrier so the barrier publishes LDS to all waves. Overwrite-safety: each
//   region is staged >=1 barrier after its last ds_read retired (LGKM0 before
//   the reader's MFMA forces retirement before it reaches its close barrier).
//   Prologue stages kt0+kt1 fully + vmcnt(0); iter0 P1/P2 redundantly restage
//   identical kt1 bytes (safe). vmcnt(0) after the loop before s_endpgm.
__global__ __launch_bounds__(512)
__attribute__((amdgpu_waves_per_eu(1, 2)))
void proj_gemm_8ph(const u16* __restrict__ X, const u16* __restrict__ W,
                   const float* __restrict__ bias, u16* __restrict__ Y)
{
    __shared__ __align__(16) u16 As[2][256 * 64];
    __shared__ __align__(16) u16 Bs[2][256 * 64];

    int bx = blockIdx.x;                  // 0..1023
    int wg = (bx & 7) * 128 + (bx >> 3);  // XCD-chunked swizzle (1024 % 8 == 0)
    int bm = wg >> 2;                     // 0..255
    int bn = wg & 3;                      // 0..3

    int tid  = threadIdx.x;
    int lane = tid & 63;
    int wid  = tid >> 6;       // 0..7
    int wm   = wid >> 2;       // 0..1
    int wn   = wid & 3;        // 0..3
    int l15  = lane & 15;
    int l4   = lane >> 4;

    const u16* Xp = X + (size_t)bm * 256 * KDIM;
    const u16* Wp = W + (size_t)bn * 256 * KDIM;

    // staging: lane covers (row_in = tid>>3 in 0..63, col16 = tid&7); the
    // global source col is XOR'd with row so linear LDS dest holds swizzled data
    int srow_in = tid >> 3;
    int scol16  = (tid & 7) ^ (srow_in & 7);

    f32x4 acc[8][4] = {};

    // one half-tile = 128 rows x 64 cols = 2 gload issues (64 rows each)
#define STAGE(lds, gbase, slot, h, kt)                                           \
    {                                                                            \
        const u16* src_ = (gbase) + (size_t)((h) * 128 + srow_in) * KDIM         \
                          + (kt) * 64 + scol16 * 8;                              \
        gload_lds16(src_, &lds[slot][((h) * 128 + wid * 8) * 64]);               \
        gload_lds16(src_ + (size_t)64 * KDIM,                                    \
                    &lds[slot][((h) * 128 + 64 + wid * 8) * 64]);                \
    }

#define READ_AF(slot, mh)                                                        \
    {                                                                            \
        _Pragma("unroll")                                                        \
        for (int mi = 0; mi < 4; ++mi) {                                         \
            int row = wm * 128 + (mh) * 64 + mi * 16 + l15;                      \
            unsigned o0 = (unsigned)(row * 128 + l4 * 16) ^ (unsigned)((row & 7) << 4); \
            af[mi][0] = *(const bf16x8*)((const char*)As[slot] + o0);            \
            af[mi][1] = *(const bf16x8*)((const char*)As[slot] + (o0 ^ 64u));    \
        }                                                                        \
    }

#define READ_BF(dst, slot, nh)                                                   \
    {                                                                            \
        _Pragma("unroll")                                                        \
        for (int ni = 0; ni < 2; ++ni) {                                         \
            int row = wn * 64 + (nh) * 32 + ni * 16 + l15;                       \
            unsigned o0 = (unsigned)(row * 128 + l4 * 16) ^ (unsigned)((row & 7) << 4); \
            dst[ni][0] = *(const bf16x8*)((const char*)Bs[slot] + o0);           \
            dst[ni][1] = *(const bf16x8*)((const char*)Bs[slot] + (o0 ^ 64u));   \
        }                                                                        \
    }

#define MFMA_Q(mlo, bb, nlo)                                                     \
    __builtin_amdgcn_s_setprio(1);                                               \
    _Pragma("unroll")                                                            \
    for (int mi = 0; mi < 4; ++mi) {                                             \
        _Pragma("unroll")                                                        \
        for (int ni = 0; ni < 2; ++ni) {                                         \
            _Pragma("unroll")                                                    \
            for (int kk = 0; kk < 2; ++kk)                                       \
                acc[(mlo) + mi][(nlo) + ni] = __builtin_amdgcn_mfma_f32_16x16x32_bf16( \
                    af[mi][kk], bb[ni][kk], acc[(mlo) + mi][(nlo) + ni], 0, 0, 0); \
        }                                                                        \
    }                                                                            \
    __builtin_amdgcn_s_setprio(0);

    // ---- prologue: kt0 -> slot0, kt1 -> slot1, full drain
    STAGE(As, Xp, 0, 0, 0);
    STAGE(As, Xp, 0, 1, 0);
    STAGE(Bs, Wp, 0, 0, 0);
    STAGE(Bs, Wp, 0, 1, 0);
    STAGE(As, Xp, 1, 0, 1);
    STAGE(As, Xp, 1, 1, 1);
    STAGE(Bs, Wp, 1, 0, 1);
    STAGE(Bs, Wp, 1, 1, 1);
    VMCNT0();
    BARRIER();

    // ---- main loop: 8 iterations x 2 K-tiles
    for (int it = 0; it < 8; ++it) {
        int c12 = 2 * it + 1;                           // As1 content (this iter's kt_b)
        int c36 = (2 * it + 2 < 16) ? 2 * it + 2 : 15;  // Bs0/As0 next content
        int c78 = (2 * it + 3 < 16) ? 2 * it + 3 : 15;  // Bs1 next content
        bf16x8 af[4][2], b0[2][2], b1[2][2];

        // P1: read s0 af-lo + b-lo; stage As1 h0 (c12)
        READ_AF(0, 0); READ_BF(b0, 0, 0);
        STAGE(As, Xp, 1, 0, c12);
        BARRIER(); LGKM0(); SCHED0();
        MFMA_Q(0, b0, 0);
        BARRIER();

        // P2: read s0 b-hi; stage As1 h1 (c12)
        READ_BF(b1, 0, 1);
        STAGE(As, Xp, 1, 1, c12);
        BARRIER(); LGKM0(); SCHED0();
        MFMA_Q(0, b1, 2);
        BARRIER();

        // P3: read s0 af-hi; stage Bs0 h0 (c36)
        READ_AF(0, 1);
        STAGE(Bs, Wp, 0, 0, c36);
        BARRIER(); LGKM0(); SCHED0();
        MFMA_Q(4, b1, 2);
        BARRIER();

        // P4: stage Bs0 h1 (c36); vmcnt(4) -> P1/P2 (As1) landed for P5
        STAGE(Bs, Wp, 0, 1, c36);
        VMCNT4(); BARRIER(); SCHED0();
        MFMA_Q(4, b0, 0);
        BARRIER();

        // P5: read s1 af-lo + b-lo; stage As0 h0 (c36)
        READ_AF(1, 0); READ_BF(b0, 1, 0);
        STAGE(As, Xp, 0, 0, c36);
        BARRIER(); LGKM0(); SCHED0();
        MFMA_Q(0, b0, 0);
        BARRIER();

        // P6: read s1 b-hi; stage As0 h1 (c36)
        READ_BF(b1, 1, 1);
        STAGE(As, Xp, 0, 1, c36);
        BARRIER(); LGKM0(); SCHED0();
        MFMA_Q(0, b1, 2);
        BARRIER();

        // P7: read s1 af-hi; stage Bs1 h0 (c78)
        READ_AF(1, 1);
        STAGE(Bs, Wp, 1, 0, c78);
        BARRIER(); LGKM0(); SCHED0();
        MFMA_Q(4, b1, 2);
        BARRIER();

        // P8: stage Bs1 h1 (c78); vmcnt(4) -> P3..P6 (Bs0+As0, c36) landed for P1'
        STAGE(Bs, Wp, 1, 1, c78);
        VMCNT4(); BARRIER(); SCHED0();
        MFMA_Q(4, b0, 0);
        BARRIER();
    }
    VMCNT0();   // drain the 2 half-tiles still in flight before epilogue/endpgm

    // ---- epilogue: + bias, bf16 store. D-frag: col(N)=l15, rows(M)=l4*4+r
#pragma unroll
    for (int ni = 0; ni < 4; ++ni) {
        int col = bn * 256 + wn * 64 + ni * 16 + l15;
        float bv = bias[col];
#pragma unroll
        for (int mi = 0; mi < 8; ++mi) {
            int row0 = bm * 256 + wm * 128 + mi * 16 + l4 * 4;
#pragma unroll
            for (int r = 0; r < 4; ++r)
                Y[(size_t)(row0 + r) * KDIM + col] = f2bf(acc[mi][ni][r] + bv);
        }
    }
#undef STAGE
#undef READ_AF
#undef READ_BF
#undef MFMA_Q
}

// ---------------- Fallback: fp32 in, convert in-loop (128^2, 2-barrier) -----
__global__ __launch_bounds__(256)
void proj_gemm(const float* __restrict__ X, const float* __restrict__ W,
               const float* __restrict__ bias, u16* __restrict__ Y)
{
    __shared__ u16 As[128 * 64];
    __shared__ u16 Bs[128 * 64];

    int bx = blockIdx.x;
    int wg = (bx & 7) * 512 + (bx >> 3);
    int bm = wg >> 3;
    int bn = wg & 7;

    int tid  = threadIdx.x;
    int lane = tid & 63;
    int wid  = tid >> 6;
    int wrow = (wid >> 1) * 64;
    int wcol = (wid & 1) * 64;
    int l15 = lane & 15;
    int l4  = lane >> 4;

    int srow = tid >> 4;
    int scol = (tid & 15) * 4;

    const float* Xp = X + (size_t)bm * 128 * KDIM;
    const float* Wp = W + (size_t)bn * 128 * KDIM;

    f32x4 acc[4][4] = {};

    for (int k0 = 0; k0 < KDIM; k0 += 64) {
        __syncthreads();
#pragma unroll
        for (int r = 0; r < 8; ++r) {
            int row = r * 16 + srow;
            vfloat4 a = *(const vfloat4*)(Xp + (size_t)row * KDIM + k0 + scol);
            vfloat4 b = *(const vfloat4*)(Wp + (size_t)row * KDIM + k0 + scol);
            ushort4v ap, bp;
#pragma unroll
            for (int j = 0; j < 4; ++j) { ap[j] = f2bf(a[j]); bp[j] = f2bf(b[j]); }
            unsigned off = (unsigned)(row * 128 + scol * 2) ^ (unsigned)((row & 7) << 4);
            *(ushort4v*)((char*)As + off) = ap;
            *(ushort4v*)((char*)Bs + off) = bp;
        }
        __syncthreads();
#pragma unroll
        for (int kk = 0; kk < 2; ++kk) {
            bf16x8 af[4], bfr[4];
#pragma unroll
            for (int mi = 0; mi < 4; ++mi) {
                int row = wrow + mi * 16 + l15;
                unsigned off = (unsigned)(row * 128 + kk * 64 + l4 * 16) ^ (unsigned)((row & 7) << 4);
                af[mi] = *(const bf16x8*)((char*)As + off);
            }
#pragma unroll
            for (int ni = 0; ni < 4; ++ni) {
                int row = wcol + ni * 16 + l15;
                unsigned off = (unsigned)(row * 128 + kk * 64 + l4 * 16) ^ (unsigned)((row & 7) << 4);
                bfr[ni] = *(const bf16x8*)((char*)Bs + off);
            }
#pragma unroll
            for (int mi = 0; mi < 4; ++mi)
#pragma unroll
                for (int ni = 0; ni < 4; ++ni)
                    acc[mi][ni] = __builtin_amdgcn_mfma_f32_16x16x32_bf16(
                        af[mi], bfr[ni], acc[mi][ni], 0, 0, 0);
        }
    }

#pragma unroll
    for (int ni = 0; ni < 4; ++ni) {
        int col = bn * 128 + wcol + ni * 16 + l15;
        float bv = bias[col];
#pragma unroll
        for (int mi = 0; mi < 4; ++mi) {
            int row0 = bm * 128 + wrow + mi * 16 + l4 * 4;
#pragma unroll
            for (int r = 0; r < 4; ++r)
                Y[(size_t)(row0 + r) * KDIM + col] = f2bf(acc[mi][ni][r] + bv);
        }
    }
}

// ---------------- Pass 2: grouped attention ----------------
__global__ __launch_bounds__(256)
void attn_kernel(const u16* __restrict__ Qg, const u16* __restrict__ Kg,
                 const u16* __restrict__ Vg, float* __restrict__ Out)
{
    __shared__ u16 Qs[128 * 64];     // [q][d] swizzled
    __shared__ u16 KVs[64 * 136];    // union: Ks [128][64] swizzled / Vt [64][136]
    __shared__ u16 Ps[128 * 136];    // [q][k], row stride 136

    int g = blockIdx.x >> 4;
    int h = blockIdx.x & 15;

    int tid  = threadIdx.x;
    int lane = tid & 63;
    int wid  = tid >> 6;
    int l15 = lane & 15, l4 = lane >> 4;
    int qbase = wid * 32;

    size_t rowbase = (size_t)g * 128 * 1024 + (size_t)h * 64;

    {
        int r  = tid >> 1;
        int c0 = (tid & 1) * 32;
        const u16* qsrc = Qg + rowbase + (size_t)r * 1024 + c0;
        const u16* ksrc = Kg + rowbase + (size_t)r * 1024 + c0;
#pragma unroll
        for (int i = 0; i < 4; ++i) {
            ushort8v qv = *(const ushort8v*)(qsrc + i * 8);
            ushort8v kv = *(const ushort8v*)(ksrc + i * 8);
            unsigned off = (unsigned)(r * 128 + (c0 + i * 8) * 2) ^ (unsigned)((r & 7) << 4);
            *(ushort8v*)((char*)Qs + off) = qv;
            *(ushort8v*)((char*)KVs + off) = kv;
        }
    }
    __syncthreads();

    f32x4 st[8][2] = {};
#pragma unroll
    for (int kk = 0; kk < 2; ++kk) {
        bf16x8 kf[8];
#pragma unroll
        for (int mi = 0; mi < 8; ++mi) {
            int row = mi * 16 + l15;
            unsigned off = (unsigned)(row * 128 + kk * 64 + l4 * 16) ^ (unsigned)((row & 7) << 4);
            kf[mi] = *(const bf16x8*)((char*)KVs + off);
        }
#pragma unroll
        for (int qi = 0; qi < 2; ++qi) {
            int row = qbase + qi * 16 + l15;
            unsigned off = (unsigned)(row * 128 + kk * 64 + l4 * 16) ^ (unsigned)((row & 7) << 4);
            bf16x8 qf = *(const bf16x8*)((char*)Qs + off);
#pragma unroll
            for (int mi = 0; mi < 8; ++mi)
                st[mi][qi] = __builtin_amdgcn_mfma_f32_16x16x32_bf16(kf[mi], qf, st[mi][qi], 0, 0, 0);
        }
    }
    __syncthreads();

    {
        int r  = tid >> 1;
        int c0 = (tid & 1) * 32;
        const u16* vsrc = Vg + rowbase + (size_t)r * 1024 + c0;
#pragma unroll
        for (int i = 0; i < 4; ++i) {
            ushort8v vv = *(const ushort8v*)(vsrc + i * 8);
#pragma unroll
            for (int e = 0; e < 8; ++e)
                KVs[(c0 + i * 8 + e) * 136 + r] = vv[e];
        }
    }

    const float cexp = 0.125f * 1.44269504088896f;
#pragma unroll
    for (int qi = 0; qi < 2; ++qi) {
        float m = -3.0e38f;
#pragma unroll
        for (int mi = 0; mi < 8; ++mi)
#pragma unroll
            for (int r = 0; r < 4; ++r) m = fmaxf(m, st[mi][qi][r]);
        m = fmaxf(m, __shfl_xor(m, 16));
        m = fmaxf(m, __shfl_xor(m, 32));
        float s = 0.f;
#pragma unroll
        for (int mi = 0; mi < 8; ++mi)
#pragma unroll
            for (int r = 0; r < 4; ++r) {
                float p = exp2f((st[mi][qi][r] - m) * cexp);
                st[mi][qi][r] = p;
                s += p;
            }
        s += __shfl_xor(s, 16);
        s += __shfl_xor(s, 32);
        float inv = 1.0f / s;
        int q = qbase + qi * 16 + l15;
#pragma unroll
        for (int mi = 0; mi < 8; ++mi) {
            ushort4v pp;
#pragma unroll
            for (int r = 0; r < 4; ++r) pp[r] = f2bf(st[mi][qi][r] * inv);
            *(ushort4v*)((char*)Ps + (unsigned)(q * 272 + mi * 32 + l4 * 8)) = pp;
        }
    }
    __syncthreads();

    f32x4 o[2][4] = {};
#pragma unroll
    for (int kk = 0; kk < 4; ++kk) {
        bf16x8 pa[2];
#pragma unroll
        for (int mf = 0; mf < 2; ++mf) {
            int q = qbase + mf * 16 + l15;
            pa[mf] = *(const bf16x8*)((char*)Ps + (unsigned)(q * 272 + kk * 64 + l4 * 16));
        }
#pragma unroll
        for (int nf = 0; nf < 4; ++nf) {
            int d = nf * 16 + l15;
            bf16x8 vb = *(const bf16x8*)((char*)KVs + (unsigned)(d * 272 + kk * 64 + l4 * 16));
#pragma unroll
            for (int mf = 0; mf < 2; ++mf)
                o[mf][nf] = __builtin_amdgcn_mfma_f32_16x16x32_bf16(pa[mf], vb, o[mf][nf], 0, 0, 0);
        }
    }

#pragma unroll
    for (int mf = 0; mf < 2; ++mf)
#pragma unroll
        for (int nf = 0; nf < 4; ++nf) {
            int d  = nf * 16 + l15;
            int q0 = qbase + mf * 16 + l4 * 4;
#pragma unroll
            for (int r = 0; r < 4; ++r)
                Out[(size_t)(g * 128 + q0 + r) * 1024 + h * 64 + d] = o[mf][nf][r];
        }
}

extern "C" void kernel_launch(void* const* d_in, const int* in_sizes, int n_in,
                              void* d_out, int out_size, void* d_ws, size_t ws_size,
                              hipStream_t stream)
{
    const float* Xq = (const float*)d_in[0];
    const float* Xk = (const float*)d_in[1];
    const float* Xv = (const float*)d_in[2];
    const float* Wq = (const float*)d_in[3];
    const float* bq = (const float*)d_in[4];
    const float* Wk = (const float*)d_in[5];
    const float* bk = (const float*)d_in[6];
    const float* Wv = (const float*)d_in[7];
    const float* bv = (const float*)d_in[8];

    const size_t NE = (size_t)NROW * KDIM;       // 67,108,864
    const size_t WE = (size_t)KDIM * KDIM;       // 1,048,576

    u16* Qw = (u16*)d_ws;
    u16* Kw = Qw + NE;
    u16* Vw = Kw + NE;

    size_t need = NE * 2 * 3 + NE * 2 + WE * 2 * 3;  // QKV + X-stage + 3 W

    if (ws_size >= need) {
        u16* Xb  = Vw + NE;          // shared X staging buffer (reused 3x)
        u16* Wb0 = Xb + NE;
        u16* Wb1 = Wb0 + WE;
        u16* Wb2 = Wb1 + WE;

        cvt_f32_bf16<<<dim3(512),  dim3(256), 0, stream>>>(Wq, Wb0, (unsigned)(WE / 8));
        cvt_f32_bf16<<<dim3(512),  dim3(256), 0, stream>>>(Wk, Wb1, (unsigned)(WE / 8));
        cvt_f32_bf16<<<dim3(512),  dim3(256), 0, stream>>>(Wv, Wb2, (unsigned)(WE / 8));

        cvt_f32_bf16<<<dim3(2048), dim3(256), 0, stream>>>(Xq, Xb, (unsigned)(NE / 8));
        proj_gemm_8ph<<<dim3(1024), dim3(512), 0, stream>>>(Xb, Wb0, bq, Qw);
        cvt_f32_bf16<<<dim3(2048), dim3(256), 0, stream>>>(Xk, Xb, (unsigned)(NE / 8));
        proj_gemm_8ph<<<dim3(1024), dim3(512), 0, stream>>>(Xb, Wb1, bk, Kw);
        cvt_f32_bf16<<<dim3(2048), dim3(256), 0, stream>>>(Xv, Xb, (unsigned)(NE / 8));
        proj_gemm_8ph<<<dim3(1024), dim3(512), 0, stream>>>(Xb, Wb2, bv, Vw);
    } else {
        proj_gemm<<<dim3(4096), dim3(256), 0, stream>>>(Xq, Wq, bq, Qw);
        proj_gemm<<<dim3(4096), dim3(256), 0, stream>>>(Xk, Wk, bk, Kw);
        proj_gemm<<<dim3(4096), dim3(256), 0, stream>>>(Xv, Wv, bv, Vw);
    }

    attn_kernel<<<dim3(512 * 16), dim3(256), 0, stream>>>(Qw, Kw, Vw, (float*)d_out);
}

// Round 11
// 846.844 us; speedup vs baseline: 1.1075x; 1.1075x over previous
//
#include <hip/hip_runtime.h>
#include <hip/hip_bf16.h>

typedef unsigned short u16;
typedef __attribute__((ext_vector_type(8))) short bf16x8;
typedef __attribute__((ext_vector_type(4))) float f32x4;
typedef __attribute__((ext_vector_type(4))) float vfloat4;
typedef __attribute__((ext_vector_type(4))) unsigned short ushort4v;
typedef __attribute__((ext_vector_type(8))) unsigned short ushort8v;

#define DEV __device__ __forceinline__
#define AS1 __attribute__((address_space(1)))
#define AS3 __attribute__((address_space(3)))

#define BARRIER()  __builtin_amdgcn_s_barrier()
#define LGKM0()    asm volatile("s_waitcnt lgkmcnt(0)" ::: "memory")
#define VMCNT0()   asm volatile("s_waitcnt vmcnt(0)" ::: "memory")
#define VMCNT4()   asm volatile("s_waitcnt vmcnt(4)" ::: "memory")
#define SCHED0()   __builtin_amdgcn_sched_barrier(0)

DEV u16 f2bf(float f) {
    union { float f; unsigned u; } v; v.f = f;
    unsigned r = v.u + 0x7FFFu + ((v.u >> 16) & 1u);
    return (u16)(r >> 16);
}

DEV void gload_lds16(const void* g, void* l) {
    __builtin_amdgcn_global_load_lds((const AS1 unsigned int*)g,
                                     (AS3 unsigned int*)l, 16, 0, 0);
}

static constexpr int KDIM = 1024;   // embed
static constexpr int NROW = 65536;  // B*S

// ---------------- fp32 -> bf16 convert (memory-bound) ----------------
__global__ __launch_bounds__(256)
void cvt_f32_bf16(const float* __restrict__ src, u16* __restrict__ dst, unsigned n8)
{
    unsigned stride = gridDim.x * blockDim.x;
    for (unsigned i = blockIdx.x * blockDim.x + threadIdx.x; i < n8; i += stride) {
        size_t base = (size_t)i * 8;
        vfloat4 a = *(const vfloat4*)(src + base);
        vfloat4 b = *(const vfloat4*)(src + base + 4);
        ushort8v o;
#pragma unroll
        for (int j = 0; j < 4; ++j) { o[j] = f2bf(a[j]); o[j + 4] = f2bf(b[j]); }
        *(ushort8v*)(dst + base) = o;
    }
}

// ---------------- 8-phase 256^2 bf16 GEMM ------------------------------------
// Same proven ledger as round 10 (full-slot granularity, vmcnt(4) at P4/P8).
// New this round: (a) MFMA_Q with kk OUTERMOST -> adjacent MFMAs independent
// (8-way ILP between dependent acc reuses); (b) coalesced epilogue: stage the
// 256x256 C-tile through LDS (reusing As as [128][256] per pass) and stream
// out 16B/lane contiguous stores. The old per-u16 scattered stores made 32B
// HBM segments -> RMW write amplification (WRITE_SIZE 250MB vs 134MB of Y).
__global__ __launch_bounds__(512)
__attribute__((amdgpu_waves_per_eu(1, 2)))
void proj_gemm_8ph(const u16* __restrict__ X, const u16* __restrict__ W,
                   const float* __restrict__ bias, u16* __restrict__ Y)
{
    __shared__ __align__(16) u16 As[2][256 * 64];
    __shared__ __align__(16) u16 Bs[2][256 * 64];

    int bx = blockIdx.x;                  // 0..1023
    int wg = (bx & 7) * 128 + (bx >> 3);  // XCD-chunked swizzle (1024 % 8 == 0)
    int bm = wg >> 2;                     // 0..255
    int bn = wg & 3;                      // 0..3

    int tid  = threadIdx.x;
    int lane = tid & 63;
    int wid  = tid >> 6;       // 0..7
    int wm   = wid >> 2;       // 0..1
    int wn   = wid & 3;        // 0..3
    int l15  = lane & 15;
    int l4   = lane >> 4;

    const u16* Xp = X + (size_t)bm * 256 * KDIM;
    const u16* Wp = W + (size_t)bn * 256 * KDIM;

    // staging: lane covers (row_in = tid>>3 in 0..63, col16 = tid&7); the
    // global source col is XOR'd with row so linear LDS dest holds swizzled data
    int srow_in = tid >> 3;
    int scol16  = (tid & 7) ^ (srow_in & 7);

    f32x4 acc[8][4] = {};

#define STAGE(lds, gbase, slot, h, kt)                                           \
    {                                                                            \
        const u16* src_ = (gbase) + (size_t)((h) * 128 + srow_in) * KDIM         \
                          + (kt) * 64 + scol16 * 8;                              \
        gload_lds16(src_, &lds[slot][((h) * 128 + wid * 8) * 64]);               \
        gload_lds16(src_ + (size_t)64 * KDIM,                                    \
                    &lds[slot][((h) * 128 + 64 + wid * 8) * 64]);                \
    }

#define READ_AF(slot, mh)                                                        \
    {                                                                            \
        _Pragma("unroll")                                                        \
        for (int mi = 0; mi < 4; ++mi) {                                         \
            int row = wm * 128 + (mh) * 64 + mi * 16 + l15;                      \
            unsigned o0 = (unsigned)(row * 128 + l4 * 16) ^ (unsigned)((row & 7) << 4); \
            af[mi][0] = *(const bf16x8*)((const char*)As[slot] + o0);            \
            af[mi][1] = *(const bf16x8*)((const char*)As[slot] + (o0 ^ 64u));    \
        }                                                                        \
    }

#define READ_BF(dst, slot, nh)                                                   \
    {                                                                            \
        _Pragma("unroll")                                                        \
        for (int ni = 0; ni < 2; ++ni) {                                         \
            int row = wn * 64 + (nh) * 32 + ni * 16 + l15;                       \
            unsigned o0 = (unsigned)(row * 128 + l4 * 16) ^ (unsigned)((row & 7) << 4); \
            dst[ni][0] = *(const bf16x8*)((const char*)Bs[slot] + o0);           \
            dst[ni][1] = *(const bf16x8*)((const char*)Bs[slot] + (o0 ^ 64u));   \
        }                                                                        \
    }

// kk outermost: the 8 MFMAs inside one kk-group touch 8 distinct acc registers
// -> fully independent issue burst; dependent reuse only across kk groups.
#define MFMA_Q(mlo, bb, nlo)                                                     \
    __builtin_amdgcn_s_setprio(1);                                               \
    _Pragma("unroll")                                                            \
    for (int kk = 0; kk < 2; ++kk) {                                             \
        _Pragma("unroll")                                                        \
        for (int mi = 0; mi < 4; ++mi) {                                         \
            _Pragma("unroll")                                                    \
            for (int ni = 0; ni < 2; ++ni)                                       \
                acc[(mlo) + mi][(nlo) + ni] = __builtin_amdgcn_mfma_f32_16x16x32_bf16( \
                    af[mi][kk], bb[ni][kk], acc[(mlo) + mi][(nlo) + ni], 0, 0, 0); \
        }                                                                        \
    }                                                                            \
    __builtin_amdgcn_s_setprio(0);

    // ---- prologue: kt0 -> slot0, kt1 -> slot1, full drain
    STAGE(As, Xp, 0, 0, 0);
    STAGE(As, Xp, 0, 1, 0);
    STAGE(Bs, Wp, 0, 0, 0);
    STAGE(Bs, Wp, 0, 1, 0);
    STAGE(As, Xp, 1, 0, 1);
    STAGE(As, Xp, 1, 1, 1);
    STAGE(Bs, Wp, 1, 0, 1);
    STAGE(Bs, Wp, 1, 1, 1);
    VMCNT0();
    BARRIER();

    // ---- main loop: 8 iterations x 2 K-tiles (ledger identical to round 10)
    for (int it = 0; it < 8; ++it) {
        int c12 = 2 * it + 1;
        int c36 = (2 * it + 2 < 16) ? 2 * it + 2 : 15;
        int c78 = (2 * it + 3 < 16) ? 2 * it + 3 : 15;
        bf16x8 af[4][2], b0[2][2], b1[2][2];

        // P1
        READ_AF(0, 0); READ_BF(b0, 0, 0);
        STAGE(As, Xp, 1, 0, c12);
        BARRIER(); LGKM0(); SCHED0();
        MFMA_Q(0, b0, 0);
        BARRIER();

        // P2
        READ_BF(b1, 0, 1);
        STAGE(As, Xp, 1, 1, c12);
        BARRIER(); LGKM0(); SCHED0();
        MFMA_Q(0, b1, 2);
        BARRIER();

        // P3
        READ_AF(0, 1);
        STAGE(Bs, Wp, 0, 0, c36);
        BARRIER(); LGKM0(); SCHED0();
        MFMA_Q(4, b1, 2);
        BARRIER();

        // P4
        STAGE(Bs, Wp, 0, 1, c36);
        VMCNT4(); BARRIER(); SCHED0();
        MFMA_Q(4, b0, 0);
        BARRIER();

        // P5
        READ_AF(1, 0); READ_BF(b0, 1, 0);
        STAGE(As, Xp, 0, 0, c36);
        BARRIER(); LGKM0(); SCHED0();
        MFMA_Q(0, b0, 0);
        BARRIER();

        // P6
        READ_BF(b1, 1, 1);
        STAGE(As, Xp, 0, 1, c36);
        BARRIER(); LGKM0(); SCHED0();
        MFMA_Q(0, b1, 2);
        BARRIER();

        // P7
        READ_AF(1, 1);
        STAGE(Bs, Wp, 1, 0, c78);
        BARRIER(); LGKM0(); SCHED0();
        MFMA_Q(4, b1, 2);
        BARRIER();

        // P8
        STAGE(Bs, Wp, 1, 1, c78);
        VMCNT4(); BARRIER(); SCHED0();
        MFMA_Q(4, b0, 0);
        BARRIER();
    }
    VMCNT0();   // every wave's in-flight gloads landed
    BARRIER();  // -> LDS content stable across all waves; safe to reuse as C-tile

    // ---- coalesced epilogue: 2 passes of 128 rows through As (64KB = [128][256])
    u16* Cs = &As[0][0];
#pragma unroll
    for (int p = 0; p < 2; ++p) {
        if (wm == p) {
#pragma unroll
            for (int ni = 0; ni < 4; ++ni) {
                float bv = bias[bn * 256 + wn * 64 + ni * 16 + l15];
#pragma unroll
                for (int mi = 0; mi < 8; ++mi) {
                    int lr0 = mi * 16 + l4 * 4;
                    int c   = wn * 64 + ni * 16 + l15;
#pragma unroll
                    for (int r = 0; r < 4; ++r)
                        Cs[(lr0 + r) * 256 + c] = f2bf(acc[mi][ni][r] + bv);
                }
            }
        }
        __syncthreads();
        // stream out: 32 threads/row x 16B = 512B contiguous per row
#pragma unroll
        for (int i = 0; i < 8; ++i) {
            int idx = tid + i * 512;          // 0..4095
            int row = idx >> 5;               // 0..127
            int c16 = idx & 31;               // 16B chunk index
            ushort8v v = *(const ushort8v*)&Cs[row * 256 + c16 * 8];
            *(ushort8v*)&Y[(size_t)(bm * 256 + p * 128 + row) * KDIM
                           + bn * 256 + c16 * 8] = v;
        }
        __syncthreads();   // pass-2 writes must wait for pass-1 reads
    }
#undef STAGE
#undef READ_AF
#undef READ_BF
#undef MFMA_Q
}

// ---------------- Fallback: fp32 in, convert in-loop (128^2, 2-barrier) -----
__global__ __launch_bounds__(256)
void proj_gemm(const float* __restrict__ X, const float* __restrict__ W,
               const float* __restrict__ bias, u16* __restrict__ Y)
{
    __shared__ u16 As[128 * 64];
    __shared__ u16 Bs[128 * 64];

    int bx = blockIdx.x;
    int wg = (bx & 7) * 512 + (bx >> 3);
    int bm = wg >> 3;
    int bn = wg & 7;

    int tid  = threadIdx.x;
    int lane = tid & 63;
    int wid  = tid >> 6;
    int wrow = (wid >> 1) * 64;
    int wcol = (wid & 1) * 64;
    int l15 = lane & 15;
    int l4  = lane >> 4;

    int srow = tid >> 4;
    int scol = (tid & 15) * 4;

    const float* Xp = X + (size_t)bm * 128 * KDIM;
    const float* Wp = W + (size_t)bn * 128 * KDIM;

    f32x4 acc[4][4] = {};

    for (int k0 = 0; k0 < KDIM; k0 += 64) {
        __syncthreads();
#pragma unroll
        for (int r = 0; r < 8; ++r) {
            int row = r * 16 + srow;
            vfloat4 a = *(const vfloat4*)(Xp + (size_t)row * KDIM + k0 + scol);
            vfloat4 b = *(const vfloat4*)(Wp + (size_t)row * KDIM + k0 + scol);
            ushort4v ap, bp;
#pragma unroll
            for (int j = 0; j < 4; ++j) { ap[j] = f2bf(a[j]); bp[j] = f2bf(b[j]); }
            unsigned off = (unsigned)(row * 128 + scol * 2) ^ (unsigned)((row & 7) << 4);
            *(ushort4v*)((char*)As + off) = ap;
            *(ushort4v*)((char*)Bs + off) = bp;
        }
        __syncthreads();
#pragma unroll
        for (int kk = 0; kk < 2; ++kk) {
            bf16x8 af[4], bfr[4];
#pragma unroll
            for (int mi = 0; mi < 4; ++mi) {
                int row = wrow + mi * 16 + l15;
                unsigned off = (unsigned)(row * 128 + kk * 64 + l4 * 16) ^ (unsigned)((row & 7) << 4);
                af[mi] = *(const bf16x8*)((char*)As + off);
            }
#pragma unroll
            for (int ni = 0; ni < 4; ++ni) {
                int row = wcol + ni * 16 + l15;
                unsigned off = (unsigned)(row * 128 + kk * 64 + l4 * 16) ^ (unsigned)((row & 7) << 4);
                bfr[ni] = *(const bf16x8*)((char*)Bs + off);
            }
#pragma unroll
            for (int mi = 0; mi < 4; ++mi)
#pragma unroll
                for (int ni = 0; ni < 4; ++ni)
                    acc[mi][ni] = __builtin_amdgcn_mfma_f32_16x16x32_bf16(
                        af[mi], bfr[ni], acc[mi][ni], 0, 0, 0);
        }
    }

#pragma unroll
    for (int ni = 0; ni < 4; ++ni) {
        int col = bn * 128 + wcol + ni * 16 + l15;
        float bv = bias[col];
#pragma unroll
        for (int mi = 0; mi < 4; ++mi) {
            int row0 = bm * 128 + wrow + mi * 16 + l4 * 4;
#pragma unroll
            for (int r = 0; r < 4; ++r)
                Y[(size_t)(row0 + r) * KDIM + col] = f2bf(acc[mi][ni][r] + bv);
        }
    }
}

// ---------------- Pass 2: grouped attention ----------------
__global__ __launch_bounds__(256)
void attn_kernel(const u16* __restrict__ Qg, const u16* __restrict__ Kg,
                 const u16* __restrict__ Vg, float* __restrict__ Out)
{
    __shared__ u16 Qs[128 * 64];     // [q][d] swizzled
    __shared__ u16 KVs[64 * 136];    // union: Ks [128][64] swizzled / Vt [64][136]
    __shared__ u16 Ps[128 * 136];    // [q][k], row stride 136

    int g = blockIdx.x >> 4;
    int h = blockIdx.x & 15;

    int tid  = threadIdx.x;
    int lane = tid & 63;
    int wid  = tid >> 6;
    int l15 = lane & 15, l4 = lane >> 4;
    int qbase = wid * 32;

    size_t rowbase = (size_t)g * 128 * 1024 + (size_t)h * 64;

    {
        int r  = tid >> 1;
        int c0 = (tid & 1) * 32;
        const u16* qsrc = Qg + rowbase + (size_t)r * 1024 + c0;
        const u16* ksrc = Kg + rowbase + (size_t)r * 1024 + c0;
#pragma unroll
        for (int i = 0; i < 4; ++i) {
            ushort8v qv = *(const ushort8v*)(qsrc + i * 8);
            ushort8v kv = *(const ushort8v*)(ksrc + i * 8);
            unsigned off = (unsigned)(r * 128 + (c0 + i * 8) * 2) ^ (unsigned)((r & 7) << 4);
            *(ushort8v*)((char*)Qs + off) = qv;
            *(ushort8v*)((char*)KVs + off) = kv;
        }
    }
    __syncthreads();

    f32x4 st[8][2] = {};
#pragma unroll
    for (int kk = 0; kk < 2; ++kk) {
        bf16x8 kf[8];
#pragma unroll
        for (int mi = 0; mi < 8; ++mi) {
            int row = mi * 16 + l15;
            unsigned off = (unsigned)(row * 128 + kk * 64 + l4 * 16) ^ (unsigned)((row & 7) << 4);
            kf[mi] = *(const bf16x8*)((char*)KVs + off);
        }
#pragma unroll
        for (int qi = 0; qi < 2; ++qi) {
            int row = qbase + qi * 16 + l15;
            unsigned off = (unsigned)(row * 128 + kk * 64 + l4 * 16) ^ (unsigned)((row & 7) << 4);
            bf16x8 qf = *(const bf16x8*)((char*)Qs + off);
#pragma unroll
            for (int mi = 0; mi < 8; ++mi)
                st[mi][qi] = __builtin_amdgcn_mfma_f32_16x16x32_bf16(kf[mi], qf, st[mi][qi], 0, 0, 0);
        }
    }
    __syncthreads();

    {
        int r  = tid >> 1;
        int c0 = (tid & 1) * 32;
        const u16* vsrc = Vg + rowbase + (size_t)r * 1024 + c0;
#pragma unroll
        for (int i = 0; i < 4; ++i) {
            ushort8v vv = *(const ushort8v*)(vsrc + i * 8);
#pragma unroll
            for (int e = 0; e < 8; ++e)
                KVs[(c0 + i * 8 + e) * 136 + r] = vv[e];
        }
    }

    const float cexp = 0.125f * 1.44269504088896f;
#pragma unroll
    for (int qi = 0; qi < 2; ++qi) {
        float m = -3.0e38f;
#pragma unroll
        for (int mi = 0; mi < 8; ++mi)
#pragma unroll
            for (int r = 0; r < 4; ++r) m = fmaxf(m, st[mi][qi][r]);
        m = fmaxf(m, __shfl_xor(m, 16));
        m = fmaxf(m, __shfl_xor(m, 32));
        float s = 0.f;
#pragma unroll
        for (int mi = 0; mi < 8; ++mi)
#pragma unroll
            for (int r = 0; r < 4; ++r) {
                float p = exp2f((st[mi][qi][r] - m) * cexp);
                st[mi][qi][r] = p;
                s += p;
            }
        s += __shfl_xor(s, 16);
        s += __shfl_xor(s, 32);
        float inv = 1.0f / s;
        int q = qbase + qi * 16 + l15;
#pragma unroll
        for (int mi = 0; mi < 8; ++mi) {
            ushort4v pp;
#pragma unroll
            for (int r = 0; r < 4; ++r) pp[r] = f2bf(st[mi][qi][r] * inv);
            *(ushort4v*)((char*)Ps + (unsigned)(q * 272 + mi * 32 + l4 * 8)) = pp;
        }
    }
    __syncthreads();

    f32x4 o[2][4] = {};
#pragma unroll
    for (int kk = 0; kk < 4; ++kk) {
        bf16x8 pa[2];
#pragma unroll
        for (int mf = 0; mf < 2; ++mf) {
            int q = qbase + mf * 16 + l15;
            pa[mf] = *(const bf16x8*)((char*)Ps + (unsigned)(q * 272 + kk * 64 + l4 * 16));
        }
#pragma unroll
        for (int nf = 0; nf < 4; ++nf) {
            int d = nf * 16 + l15;
            bf16x8 vb = *(const bf16x8*)((char*)KVs + (unsigned)(d * 272 + kk * 64 + l4 * 16));
#pragma unroll
            for (int mf = 0; mf < 2; ++mf)
                o[mf][nf] = __builtin_amdgcn_mfma_f32_16x16x32_bf16(pa[mf], vb, o[mf][nf], 0, 0, 0);
        }
    }

#pragma unroll
    for (int mf = 0; mf < 2; ++mf)
#pragma unroll
        for (int nf = 0; nf < 4; ++nf) {
            int d  = nf * 16 + l15;
            int q0 = qbase + mf * 16 + l4 * 4;
#pragma unroll
            for (int r = 0; r < 4; ++r)
                Out[(size_t)(g * 128 + q0 + r) * 1024 + h * 64 + d] = o[mf][nf][r];
        }
}

extern "C" void kernel_launch(void* const* d_in, const int* in_sizes, int n_in,
                              void* d_out, int out_size, void* d_ws, size_t ws_size,
                              hipStream_t stream)
{
    const float* Xq = (const float*)d_in[0];
    const float* Xk = (const float*)d_in[1];
    const float* Xv = (const float*)d_in[2];
    const float* Wq = (const float*)d_in[3];
    const float* bq = (const float*)d_in[4];
    const float* Wk = (const float*)d_in[5];
    const float* bk = (const float*)d_in[6];
    const float* Wv = (const float*)d_in[7];
    const float* bv = (const float*)d_in[8];

    const size_t NE = (size_t)NROW * KDIM;       // 67,108,864
    const size_t WE = (size_t)KDIM * KDIM;       // 1,048,576

    u16* Qw = (u16*)d_ws;
    u16* Kw = Qw + NE;
    u16* Vw = Kw + NE;

    size_t need = NE * 2 * 3 + NE * 2 + WE * 2 * 3;  // QKV + X-stage + 3 W

    if (ws_size >= need) {
        u16* Xb  = Vw + NE;          // shared X staging buffer (reused 3x)
        u16* Wb0 = Xb + NE;
        u16* Wb1 = Wb0 + WE;
        u16* Wb2 = Wb1 + WE;

        cvt_f32_bf16<<<dim3(512),  dim3(256), 0, stream>>>(Wq, Wb0, (unsigned)(WE / 8));
        cvt_f32_bf16<<<dim3(512),  dim3(256), 0, stream>>>(Wk, Wb1, (unsigned)(WE / 8));
        cvt_f32_bf16<<<dim3(512),  dim3(256), 0, stream>>>(Wv, Wb2, (unsigned)(WE / 8));

        cvt_f32_bf16<<<dim3(2048), dim3(256), 0, stream>>>(Xq, Xb, (unsigned)(NE / 8));
        proj_gemm_8ph<<<dim3(1024), dim3(512), 0, stream>>>(Xb, Wb0, bq, Qw);
        cvt_f32_bf16<<<dim3(2048), dim3(256), 0, stream>>>(Xk, Xb, (unsigned)(NE / 8));
        proj_gemm_8ph<<<dim3(1024), dim3(512), 0, stream>>>(Xb, Wb1, bk, Kw);
        cvt_f32_bf16<<<dim3(2048), dim3(256), 0, stream>>>(Xv, Xb, (unsigned)(NE / 8));
        proj_gemm_8ph<<<dim3(1024), dim3(512), 0, stream>>>(Xb, Wb2, bv, Vw);
    } else {
        proj_gemm<<<dim3(4096), dim3(256), 0, stream>>>(Xq, Wq, bq, Qw);
        proj_gemm<<<dim3(4096), dim3(256), 0, stream>>>(Xk, Wk, bk, Kw);
        proj_gemm<<<dim3(4096), dim3(256), 0, stream>>>(Xv, Wv, bv, Vw);
    }

    attn_kernel<<<dim3(512 * 16), dim3(256), 0, stream>>>(Qw, Kw, Vw, (float*)d_out);
}